// Round 1
// baseline (45.399 us; speedup 1.0000x reference)
//
#include <hip/hip_runtime.h>

// y = (x_f - x_i)^T (W @ x_i)  — scalar output.
// HBM-bound on W (256 MiB read once). One wave per row, float4 loads,
// deterministic two-pass reduction (no atomics).

#define NDIM 8192
#define THREADS 256
#define WAVES_PER_BLOCK 4
#define BLOCKS (NDIM / WAVES_PER_BLOCK)   // 2048

__global__ __launch_bounds__(THREADS) void dyn_rowdot_kernel(
    const float* __restrict__ W,
    const float* __restrict__ x_i,
    const float* __restrict__ x_f,
    float* __restrict__ partial) {
  const int wave = threadIdx.x >> 6;   // 0..3
  const int lane = threadIdx.x & 63;
  const int row = blockIdx.x * WAVES_PER_BLOCK + wave;

  const float4* __restrict__ Wrow =
      reinterpret_cast<const float4*>(W + (size_t)row * NDIM);
  const float4* __restrict__ X = reinterpret_cast<const float4*>(x_i);

  float acc = 0.0f;
  // NDIM/4 float4 per row = 2048; /64 lanes = 32 iterations.
#pragma unroll 4
  for (int it = 0; it < (NDIM / 4) / 64; ++it) {
    const float4 w = Wrow[it * 64 + lane];
    const float4 x = X[it * 64 + lane];
    acc = fmaf(w.x, x.x, acc);
    acc = fmaf(w.y, x.y, acc);
    acc = fmaf(w.z, x.z, acc);
    acc = fmaf(w.w, x.w, acc);
  }

  // wave (64-lane) butterfly reduction
#pragma unroll
  for (int off = 32; off > 0; off >>= 1) acc += __shfl_xor(acc, off, 64);

  __shared__ float wsum[WAVES_PER_BLOCK];
  if (lane == 0) wsum[wave] = acc * (x_f[row] - x_i[row]);
  __syncthreads();
  if (threadIdx.x == 0)
    partial[blockIdx.x] = (wsum[0] + wsum[1]) + (wsum[2] + wsum[3]);
}

__global__ __launch_bounds__(THREADS) void dyn_reduce_kernel(
    const float* __restrict__ partial, float* __restrict__ out) {
  float acc = 0.0f;
  for (int i = threadIdx.x; i < BLOCKS; i += THREADS) acc += partial[i];
#pragma unroll
  for (int off = 32; off > 0; off >>= 1) acc += __shfl_xor(acc, off, 64);
  __shared__ float wsum[WAVES_PER_BLOCK];
  const int wave = threadIdx.x >> 6;
  const int lane = threadIdx.x & 63;
  if (lane == 0) wsum[wave] = acc;
  __syncthreads();
  if (threadIdx.x == 0)
    out[0] = (wsum[0] + wsum[1]) + (wsum[2] + wsum[3]);
}

extern "C" void kernel_launch(void* const* d_in, const int* in_sizes, int n_in,
                              void* d_out, int out_size, void* d_ws, size_t ws_size,
                              hipStream_t stream) {
  const float* x_i = (const float*)d_in[0];
  const float* x_f = (const float*)d_in[1];
  const float* W   = (const float*)d_in[2];
  // d_in[3] = t (unused numerically), d_in[4] = arg (unused)

  float* partial = (float*)d_ws;        // needs BLOCKS*4 = 8 KiB of scratch
  float* out     = (float*)d_out;

  dyn_rowdot_kernel<<<BLOCKS, THREADS, 0, stream>>>(W, x_i, x_f, partial);
  dyn_reduce_kernel<<<1, THREADS, 0, stream>>>(partial, out);
}